// Round 3
// baseline (262.497 us; speedup 1.0000x reference)
//
#include <hip/hip_runtime.h>
#include <hip/hip_bf16.h>
#include <stdint.h>

#define WW   361     // W*W spatial positions
#define CCH  64      // channels (K)
#define MH   192     // support rows per block (i-half)
#define NP   368     // query rows padded to 23 tiles of 16
#define NBS  600     // B*S
#define NTHR 576     // 9 waves: 560 staged rows, each thread owns <= 1 row

typedef __attribute__((ext_vector_type(8))) short short8;
typedef __attribute__((ext_vector_type(4))) float f32x4;

// LDS layout: row-major [row][k], pitch 64 bf16 (128B), 16B-chunk XOR swizzle:
// element (m,k) at m*64 + ((k/8 ^ (m&7))*8) + (k&7). b128 stores and b128
// fragment reads both bank-uniform (R1: SQ_LDS_BANK_CONFLICT == 0).

// Stage one row: 64 floats strided by WW, bf16-pack into dst (= sh + m*CCH),
// return rsqrt(sum of squares). Two 32-deep load batches for MLP.
__device__ __forceinline__ float stage_row(const float* __restrict__ gp,
                                           unsigned short* __restrict__ dst, int sw) {
  float a0 = 0.f, a1 = 0.f, a2 = 0.f, a3 = 0.f;
  #pragma unroll
  for (int h = 0; h < 2; ++h) {
    float v[32];
    #pragma unroll
    for (int j = 0; j < 32; ++j) v[j] = gp[(h * 32 + j) * WW];  // coalesced across lanes
    #pragma unroll
    for (int j = 0; j < 32; j += 4) {
      a0 += v[j] * v[j];     a1 += v[j+1] * v[j+1];
      a2 += v[j+2] * v[j+2]; a3 += v[j+3] * v[j+3];
    }
    #pragma unroll
    for (int c0 = 0; c0 < 4; ++c0) {
      const int c = h * 4 + c0;
      unsigned int u[4];
      #pragma unroll
      for (int jj = 0; jj < 4; ++jj) {
        __hip_bfloat162 b2 =
            __float22bfloat162_rn(make_float2(v[c0 * 8 + 2 * jj], v[c0 * 8 + 2 * jj + 1]));
        u[jj] = *(unsigned int*)&b2;
      }
      *(uint4*)&dst[(c ^ sw) * 8] = make_uint4(u[0], u[1], u[2], u[3]);
    }
  }
  return rsqrtf(a0 + a1 + a2 + a3);
}

__device__ __forceinline__ void zero_row(unsigned short* __restrict__ dst) {
  #pragma unroll
  for (int c = 0; c < 8; ++c)
    *(uint4*)&dst[c * 8] = make_uint4(0u, 0u, 0u, 0u);
}

__global__ __launch_bounds__(NTHR, 4) void cossim_max_kernel(
    const float* __restrict__ support, const float* __restrict__ query,
    float* __restrict__ out)
{
  __shared__ __align__(16) unsigned short S_sh[MH * CCH];  // 24576 B
  __shared__ __align__(16) unsigned short Q_sh[NP * CCH];  // 47104 B
  __shared__ float inv_s[MH];                              //   768 B
  __shared__ float inv_q[NP];                              //  1472 B -> 73920 B total (2 blocks/CU)

  const int tid   = threadIdx.x;
  const int bs    = blockIdx.x >> 1;
  const int half  = blockIdx.x & 1;
  const int mBase = half * MH;

  const float* sg = support + (size_t)bs * (WW * CCH);
  const float* qg = query   + (size_t)bs * (WW * CCH);

  // ---- Staging: each thread owns at most one row; single barrier ----
  if (tid < NP) {                       // waves 0-5: query rows
    const int m = tid;
    if (m < WW) {
      inv_q[m] = stage_row(qg + m, &Q_sh[m * CCH], m & 7);
    } else {
      zero_row(&Q_sh[m * CCH]);         // pad rows: acc==0 -> bias trick
      inv_q[m] = 0.f;
    }
  } else if (tid >= 384) {              // waves 6-8: support rows (wave-aligned)
    const int mL = tid - 384;           // 0..191
    const int mG = mBase + mL;
    if (mG < WW) {
      inv_s[mL] = stage_row(sg + mG, &S_sh[mL * CCH], mL & 7);
    } else {
      zero_row(&S_sh[mL * CCH]);        // keep MFMA inputs NaN-free
      inv_s[mL] = 0.f;
    }
  }
  __syncthreads();

  // ---- Compute: 12 i-tiles of 16 rows over 9 waves ----
  const int lane = tid & 63;
  const int wv   = tid >> 6;     // 0..8
  const int l15  = lane & 15;
  const int quad = lane >> 4;    // 0..3

  for (int tile = wv; tile < MH / 16; tile += 9) {
    // A fragment: A[m = l15][k = quad*8+j]; k-half s covers k in [s*32, s*32+32)
    short8 af[2];
    const int m = 16 * tile + l15;
    #pragma unroll
    for (int s = 0; s < 2; ++s) {
      const int c = 4 * s + quad;
      af[s] = *(const short8*)&S_sh[m * CCH + ((c ^ (m & 7)) * 8)];
    }

    f32x4 mx = {-3e38f, -3e38f, -3e38f, -3e38f};

    for (int pt = 0; pt < NP / 16; ++pt) {
      const int n  = 16 * pt + l15;
      const int sw = l15 & 7;                 // == n&7 (16*pt ≡ 0 mod 8)
      short8 b0 = *(const short8*)&Q_sh[n * CCH + (((0 + quad) ^ sw) * 8)];
      short8 b1 = *(const short8*)&Q_sh[n * CCH + (((4 + quad) ^ sw) * 8)];
      f32x4 acc = {0.f, 0.f, 0.f, 0.f};
      acc = __builtin_amdgcn_mfma_f32_16x16x32_bf16(af[0], b0, acc, 0, 0, 0);
      acc = __builtin_amdgcn_mfma_f32_16x16x32_bf16(af[1], b1, acc, 0, 0, 0);
      const float qs   = inv_q[n];
      const float bias = (n < WW) ? 0.f : -1e30f;  // pad p never wins
      #pragma unroll
      for (int r = 0; r < 4; ++r) mx[r] = fmaxf(mx[r], acc[r] * qs + bias);
    }

    // max over columns (C layout: col = lane&15): butterfly within 16-lane group
    #pragma unroll
    for (int d = 1; d < 16; d <<= 1) {
      #pragma unroll
      for (int r = 0; r < 4; ++r) mx[r] = fmaxf(mx[r], __shfl_xor(mx[r], d));
    }

    // C/D layout: row = quad*4 + reg; one writer lane per 16-lane group
    if (l15 == 0) {
      #pragma unroll
      for (int r = 0; r < 4; ++r) {
        const int mL = 16 * tile + 4 * quad + r;
        const int iG = mBase + mL;
        if (iG < WW) out[(size_t)bs * WW + iG] = mx[r] * inv_s[mL];
      }
    }
  }
}

extern "C" void kernel_launch(void* const* d_in, const int* in_sizes, int n_in,
                              void* d_out, int out_size, void* d_ws, size_t ws_size,
                              hipStream_t stream) {
  const float* support = (const float*)d_in[0];
  const float* query   = (const float*)d_in[1];
  float* out = (float*)d_out;
  dim3 grid(NBS * 2), block(NTHR);
  hipLaunchKernelGGL(cossim_max_kernel, grid, block, 0, stream,
                     support, query, out);
}

// Round 4
// 137.222 us; speedup vs baseline: 1.9129x; 1.9129x over previous
//
#include <hip/hip_runtime.h>
#include <hip/hip_bf16.h>
#include <stdint.h>

#define WW   361     // W*W spatial positions
#define CCH  64      // channels (K)
#define MH   192     // support rows per block (i-half)
#define NP   368     // query rows padded to 23 tiles of 16
#define NBS  600     // B*S
#define NTHR 768     // 12 waves: 553 staged rows in one pass; 12 compute tiles, 1/wave

typedef __attribute__((ext_vector_type(8))) short short8;
typedef __attribute__((ext_vector_type(4))) float f32x4;

// LDS layout: row-major [row][k], pitch 64 bf16 (128B), 16B-chunk XOR swizzle:
// element (m,k) at m*64 + ((k/8 ^ (m&7))*8) + (k&7). b128 stores and b128
// fragment reads both bank-uniform (R1/R2: SQ_LDS_BANK_CONFLICT ~ 0).

// Stage one row: 64 floats strided by WW, bf16-pack into dst (= sh + m*CCH),
// return rsqrt(sum of squares). R1-proven spill-free shape: 8 chunks of v[8]
// (VGPR 68, WRITE_SIZE = output-only). Do NOT widen to v[32] — R3 spilled
// (WRITE_SIZE 314 MB scratch traffic, occupancy collapse).
__device__ __forceinline__ float stage_row(const float* __restrict__ gp,
                                           unsigned short* __restrict__ dst, int sw) {
  float a0 = 0.f, a1 = 0.f, a2 = 0.f, a3 = 0.f;
  #pragma unroll
  for (int c = 0; c < 8; ++c) {
    float v[8];
    #pragma unroll
    for (int j = 0; j < 8; ++j) v[j] = gp[(c * 8 + j) * WW];  // coalesced across lanes
    unsigned int u[4];
    #pragma unroll
    for (int jj = 0; jj < 4; ++jj) {
      a0 += v[2*jj] * v[2*jj];
      a1 += v[2*jj+1] * v[2*jj+1];
      __hip_bfloat162 b2 =
          __float22bfloat162_rn(make_float2(v[2*jj], v[2*jj+1]));
      u[jj] = *(unsigned int*)&b2;
    }
    *(uint4*)&dst[(c ^ sw) * 8] = make_uint4(u[0], u[1], u[2], u[3]);
  }
  return rsqrtf((a0 + a1) + (a2 + a3));
}

__device__ __forceinline__ void zero_row(unsigned short* __restrict__ dst) {
  #pragma unroll
  for (int c = 0; c < 8; ++c)
    *(uint4*)&dst[c * 8] = make_uint4(0u, 0u, 0u, 0u);
}

__global__ __launch_bounds__(NTHR, 6) void cossim_max_kernel(
    const float* __restrict__ support, const float* __restrict__ query,
    float* __restrict__ out)
{
  __shared__ __align__(16) unsigned short S_sh[MH * CCH];  // 24576 B
  __shared__ __align__(16) unsigned short Q_sh[NP * CCH];  // 47104 B
  __shared__ float inv_s[MH];                              //   768 B
  __shared__ float inv_q[NP];                              //  1472 B -> 73920 B (2 blocks/CU)

  const int tid   = threadIdx.x;
  const int bs    = blockIdx.x >> 1;
  const int half  = blockIdx.x & 1;
  const int mBase = half * MH;

  const float* sg = support + (size_t)bs * (WW * CCH);
  const float* qg = query   + (size_t)bs * (WW * CCH);

  // ---- Staging: every row owned by exactly one thread; ONE barrier total ----
  if (tid < NP) {                       // Q rows 0..367
    const int m = tid;
    if (m < WW) {
      inv_q[m] = stage_row(qg + m, &Q_sh[m * CCH], m & 7);
    } else {
      zero_row(&Q_sh[m * CCH]);         // pad rows: acc==0 -> bias trick
      inv_q[m] = 0.f;
    }
  } else if (tid < NP + MH) {           // S rows 0..191
    const int mL = tid - NP;
    const int mG = mBase + mL;
    if (mG < WW) {
      inv_s[mL] = stage_row(sg + mG, &S_sh[mL * CCH], mL & 7);
    } else {
      zero_row(&S_sh[mL * CCH]);        // keep MFMA inputs NaN-free
      inv_s[mL] = 0.f;
    }
  }
  __syncthreads();

  // ---- Compute: wave wv owns i-tile wv (rows 16wv..16wv+15) ----
  const int lane = tid & 63;
  const int wv   = tid >> 6;     // 0..11 -> exactly the 12 tiles
  const int l15  = lane & 15;
  const int quad = lane >> 4;    // 0..3

  // A fragment: A[m = l15][k = quad*8+j]; k-half s covers k in [s*32, s*32+32)
  short8 af[2];
  {
    const int m = 16 * wv + l15;
    #pragma unroll
    for (int s = 0; s < 2; ++s) {
      const int c = 4 * s + quad;
      af[s] = *(const short8*)&S_sh[m * CCH + ((c ^ (m & 7)) * 8)];
    }
  }

  f32x4 mx = {-3e38f, -3e38f, -3e38f, -3e38f};

  for (int pt = 0; pt < NP / 16; ++pt) {
    const int n  = 16 * pt + l15;
    const int sw = l15 & 7;                 // == n&7 (16*pt ≡ 0 mod 8)
    short8 b0 = *(const short8*)&Q_sh[n * CCH + (((0 + quad) ^ sw) * 8)];
    short8 b1 = *(const short8*)&Q_sh[n * CCH + (((4 + quad) ^ sw) * 8)];
    f32x4 acc = {0.f, 0.f, 0.f, 0.f};
    acc = __builtin_amdgcn_mfma_f32_16x16x32_bf16(af[0], b0, acc, 0, 0, 0);
    acc = __builtin_amdgcn_mfma_f32_16x16x32_bf16(af[1], b1, acc, 0, 0, 0);
    const float qs   = inv_q[n];
    const float bias = (n < WW) ? 0.f : -1e30f;  // pad p never wins
    #pragma unroll
    for (int r = 0; r < 4; ++r) mx[r] = fmaxf(mx[r], acc[r] * qs + bias);
  }

  // max over columns (C layout: col = lane&15): butterfly within 16-lane group
  #pragma unroll
  for (int d = 1; d < 16; d <<= 1) {
    #pragma unroll
    for (int r = 0; r < 4; ++r) mx[r] = fmaxf(mx[r], __shfl_xor(mx[r], d));
  }

  // C/D layout: row = quad*4 + reg; one writer lane per 16-lane group
  if (l15 == 0) {
    #pragma unroll
    for (int r = 0; r < 4; ++r) {
      const int mL = 16 * wv + 4 * quad + r;
      const int iG = mBase + mL;
      if (iG < WW) out[(size_t)bs * WW + iG] = mx[r] * inv_s[mL];
    }
  }
}

extern "C" void kernel_launch(void* const* d_in, const int* in_sizes, int n_in,
                              void* d_out, int out_size, void* d_ws, size_t ws_size,
                              hipStream_t stream) {
  const float* support = (const float*)d_in[0];
  const float* query   = (const float*)d_in[1];
  float* out = (float*)d_out;
  dim3 grid(NBS * 2), block(NTHR);
  hipLaunchKernelGGL(cossim_max_kernel, grid, block, 0, stream,
                     support, query, out);
}